// Round 1
// baseline (7500.108 us; speedup 1.0000x reference)
//
#include <hip/hip_runtime.h>
#include <math.h>

#define N_RES 2048
#define N_IN  128
#define T_SEQ 2048
#define NB    128      // blocks in recurrence kernel
#define ROWS  16       // rows per block (fallback kernel)
#define SENTMASK64 0x4000000040000000ULL   // bit30 sentinel test, both dwords

// ---------------- Kernel 1: U = input @ W_in^T (fallback path only) -------
__global__ __launch_bounds__(256) void u_gemm(
    const float* __restrict__ in, const float* __restrict__ win,
    float* __restrict__ out)
{
  __shared__ float As[64][65];
  __shared__ float Bs[64][65];
  const int tid = threadIdx.x;
  const int t0 = blockIdx.y * 64;
  const int n0 = blockIdx.x * 64;
  const int tx = tid & 15, ty = tid >> 4;

  float acc[4][4];
  #pragma unroll
  for (int r = 0; r < 4; ++r)
    #pragma unroll
    for (int c = 0; c < 4; ++c) acc[r][c] = 0.f;

  for (int k0 = 0; k0 < N_IN; k0 += 64) {
    __syncthreads();
    #pragma unroll
    for (int i = 0; i < 4; ++i) {
      int idx = tid + i * 256;
      int row = idx >> 4;
      int k4  = (idx & 15) << 2;
      float4 a = *(const float4*)(in  + (size_t)(t0 + row) * N_IN + k0 + k4);
      As[row][k4+0] = a.x; As[row][k4+1] = a.y; As[row][k4+2] = a.z; As[row][k4+3] = a.w;
      float4 b = *(const float4*)(win + (size_t)(n0 + row) * N_IN + k0 + k4);
      Bs[row][k4+0] = b.x; Bs[row][k4+1] = b.y; Bs[row][k4+2] = b.z; Bs[row][k4+3] = b.w;
    }
    __syncthreads();
    for (int k = 0; k < 64; ++k) {
      float a[4], b[4];
      #pragma unroll
      for (int r = 0; r < 4; ++r) a[r] = As[ty*4+r][k];
      #pragma unroll
      for (int c = 0; c < 4; ++c) b[c] = Bs[tx*4+c][k];
      #pragma unroll
      for (int r = 0; r < 4; ++r)
        #pragma unroll
        for (int c = 0; c < 4; ++c) acc[r][c] += a[r] * b[c];
    }
  }
  #pragma unroll
  for (int r = 0; r < 4; ++r) {
    float4 v = make_float4(acc[r][0], acc[r][1], acc[r][2], acc[r][3]);
    *(float4*)(out + (size_t)(t0 + ty*4 + r) * N_RES + n0 + tx*4) = v;
  }
}

// ---- DPP helpers ----------------------------------------------------------
template<int CTRL>
__device__ __forceinline__ float xdpp(float v)
{
  return __uint_as_float(__builtin_amdgcn_update_dpp(
      0, (int)__float_as_uint(v), CTRL, 0xF, 0xF, true));
}
// quad_perm[1,0,3,2] (xor1) = 0xB1 ; quad_perm[2,3,0,1] (xor2) = 0x4E
// row_ror:8 = 0x128 : within 16-lane rows, (i+8)%16 == i^8

// ---- 4-row fold-and-keep wave reduction -----------------------------------
// v[0..3] are per-lane partials of 4 rows. After 2 fold stages + xor4/8/16/32
// sums, every lane holds the FULL sum of row rml2(lane&3) where
// rml2(L) = (L&1)*2 + ((L>>1)&1)  (bijection on 0..3).
__device__ __forceinline__ float fold_reduce4(float v[4], int lane)
{
  #pragma unroll
  for (int r = 0; r < 2; ++r) {
    float send = (lane & 1) ? v[r] : v[r + 2];
    float recv = xdpp<0xB1>(send);
    v[r] = ((lane & 1) ? v[r + 2] : v[r]) + recv;
  }
  {
    float send = (lane & 2) ? v[0] : v[1];
    float recv = xdpp<0x4E>(send);
    v[0] = ((lane & 2) ? v[1] : v[0]) + recv;
  }
  v[0] += __shfl_xor(v[0], 4, 64);
  v[0] += xdpp<0x128>(v[0]);           // xor8 within 16-lane row
  v[0] += __shfl_xor(v[0], 16, 64);
  v[0] += __shfl_xor(v[0], 32, 64);
  return v[0];
}

// ---- branchless fast erf (A&S 7.1.26), abs err <= 1.5e-7 ------------------
// 1/x via v_rcp_f32 (1 ULP): removes the full-precision division sequence
// (div_scale/div_fmas/div_fixup, ~10 dependent ops) from the finalize
// critical path. exp underflow at large |a| gives exactly +-1.
__device__ __forceinline__ float fast_erf(float a)
{
  float ax = fabsf(a);
  float t  = __builtin_amdgcn_rcpf(fmaf(0.3275911f, ax, 1.0f));
  float p  = fmaf(1.061405429f, t, -1.453152027f);
  p = fmaf(p, t, 1.421413741f);
  p = fmaf(p, t, -0.284496736f);
  p = fmaf(p, t, 0.254829592f);
  p *= t;
  float e = __expf(-ax * ax);
  float r = fmaf(-p, e, 1.0f);
  return copysignf(r, a);
}

// ---- in-kernel U: u[row] = dot(W_in[row,:], input[t,:]) -------------------
// lane handles input cols {lane, lane+64}; 8 FMAs + 4-row fold. Executed
// AFTER publish(t) so it hides entirely under the next step's poll.
__device__ __forceinline__ float compute_u(const float (&wi)[4][2],
                                           float ia, float ib, int lane)
{
  float v[4];
  #pragma unroll
  for (int r = 0; r < 4; ++r)
    v[r] = fmaf(wi[r][0], ia, wi[r][1] * ib);
  return fold_reduce4(v, lane);
}

template<int RREP>
__device__ __forceinline__ void publish(unsigned int* __restrict__ xbuf,
                                        float* __restrict__ out,
                                        int t, int row, int lane, float x)
{
  if (lane < 4) {
    unsigned int xu = __float_as_uint(x);
    unsigned int* dst = xbuf + (size_t)t * RREP * N_RES + row;
    #pragma unroll
    for (int rep = 0; rep < RREP; ++rep)
      __hip_atomic_store(dst + (size_t)rep * N_RES, xu,
                         __ATOMIC_RELAXED, __HIP_MEMORY_SCOPE_AGENT);
    out[(size_t)t * N_RES + row] = x;   // plain store; after signals
  }
}

// ---------------- Kernel 2: recurrence v13 — wave-autonomous ---------------
// 128 blocks x 256 threads = 512 waves; global wave g owns rows [4g,4g+4).
// Each wave polls the ENTIRE previous x row (16 x 64-bit sentinel loads per
// lane), reduces its 4 rows fully in-register (fold_reduce4), finalizes and
// publishes with NO LDS and NO barriers anywhere. U computed in-kernel after
// publish (hidden under next poll). Data-as-flag sentinel, fresh lines per
// step, RREP replicas (fan-in 512/RREP waves per line).
template<int RREP>
__global__ __launch_bounds__(256, 1) void esn_recur_v13(
    const float* __restrict__ in, const float* __restrict__ win,
    const float* __restrict__ wres, float* __restrict__ out,
    unsigned int* __restrict__ xbuf)
{
  const int tid  = threadIdx.x;
  const int lane = tid & 63;
  const int wave = tid >> 6;
  const int gw   = blockIdx.x * 4 + wave;       // 0..511
  const int row0 = gw * 4;
  const int rb   = gw & (RREP - 1);             // replica this wave polls
  const float invs = 0.022097086912079608f;     // 1/sqrt(2048)
  const int rml = (lane & 1) * 2 + ((lane >> 1) & 1);

  // ---- W_in fragment + t=0 publish FIRST (unblocks everyone's t=1 poll) --
  float wi[4][2];
  #pragma unroll
  for (int r = 0; r < 4; ++r) {
    wi[r][0] = win[(size_t)(row0 + r) * N_IN + lane];
    wi[r][1] = win[(size_t)(row0 + r) * N_IN + 64 + lane];
  }
  float ia = in[lane], ib = in[64 + lane];
  {
    float u0 = compute_u(wi, ia, ib, lane);
    float x0 = fast_erf(u0) * invs;
    publish<RREP>(xbuf, out, 0, row0 + rml, lane, x0);
  }

  // ---- W_res fragment: w[r][2j+k] = W[row0+r][2*lane + 128*j + k] --------
  float w[4][32];
  #pragma unroll
  for (int r = 0; r < 4; ++r) {
    const float* p = wres + (size_t)(row0 + r) * N_RES + 2 * lane;
    #pragma unroll
    for (int j = 0; j < 16; ++j) {
      float2 v = *(const float2*)(p + 128 * j);
      w[r][2*j]   = v.x;
      w[r][2*j+1] = v.y;
    }
  }

  // pipeline: u for t=1 ready; input row for t=2 in flight
  ia = in[N_IN + lane]; ib = in[N_IN + 64 + lane];
  float u = compute_u(wi, ia, ib, lane);
  ia = in[2 * N_IN + lane]; ib = in[2 * N_IN + 64 + lane];

  for (int t = 1; t < T_SEQ; ++t) {
    // ---- poll full previous row: 16 x u64 words (cols 2*lane+128j) -------
    const unsigned long long* xr = (const unsigned long long*)xbuf
        + ((size_t)(t - 1) * RREP + rb) * (N_RES / 2) + lane;
    unsigned long long xb[16];
    unsigned long long orv;
    do {
      #pragma unroll
      for (int j = 0; j < 16; ++j)
        xb[j] = __hip_atomic_load(xr + (size_t)j * 64, __ATOMIC_RELAXED,
                                  __HIP_MEMORY_SCOPE_AGENT);
      unsigned long long o0 = (xb[0] | xb[1]) | (xb[2] | xb[3]);
      unsigned long long o1 = (xb[4] | xb[5]) | (xb[6] | xb[7]);
      unsigned long long o2 = (xb[8] | xb[9]) | (xb[10] | xb[11]);
      unsigned long long o3 = (xb[12] | xb[13]) | (xb[14] | xb[15]);
      orv = (o0 | o1) | (o2 | o3);
    } while (orv & SENTMASK64);

    asm volatile("s_setprio 3" ::: "memory");   // critical path begins

    float acc[4] = {0.f, 0.f, 0.f, 0.f};
    #pragma unroll
    for (int j = 0; j < 16; ++j) {
      float xlo = __uint_as_float((unsigned int)xb[j]);
      float xhi = __uint_as_float((unsigned int)(xb[j] >> 32));
      #pragma unroll
      for (int r = 0; r < 4; ++r)
        acc[r] = fmaf(w[r][2*j+1], xhi, fmaf(w[r][2*j], xlo, acc[r]));
    }
    float s  = fold_reduce4(acc, lane);          // full row sum, row rml
    float xt = fast_erf(u + s) * invs;
    publish<RREP>(xbuf, out, t, row0 + rml, lane, xt);

    asm volatile("s_setprio 0" ::: "memory");    // back to poll priority

    // ---- u for t+1, input row for t+2: hidden under the next poll --------
    u = compute_u(wi, ia, ib, lane);
    int tn = (t + 2 < T_SEQ) ? t + 2 : T_SEQ - 1;
    ia = in[(size_t)tn * N_IN + lane];
    ib = in[(size_t)tn * N_IN + 64 + lane];
  }
}

// ---------------- fallback (R2 flag barrier) if ws too small ---------------
#define FSTR 4
__global__ __launch_bounds__(256, 1) void esn_recur_flags(
    const float* __restrict__ wres, float* out, int* ws)
{
  const int b = blockIdx.x;
  const int tid = threadIdx.x;
  const int lane = tid & 63;
  const int wave = tid >> 6;
  const int row0 = b * ROWS;
  const float inv = 0.022097086912079608f;

  float w[ROWS][8];
  #pragma unroll
  for (int r = 0; r < ROWS; ++r) {
    const float* p = wres + (size_t)(row0 + r) * N_RES + tid;
    #pragma unroll
    for (int j = 0; j < 8; ++j) w[r][j] = p[j * 256];
  }

  __shared__ float red[ROWS][4];
  int* flags = ws;

  if (tid < ROWS) {
    float u = out[row0 + tid];
    __hip_atomic_store(out + row0 + tid, erff(u) * inv,
                       __ATOMIC_RELAXED, __HIP_MEMORY_SCOPE_AGENT);
  }
  if (wave == 0) {
    asm volatile("s_waitcnt vmcnt(0)" ::: "memory");
    if (lane == 0)
      __hip_atomic_store(flags + b * FSTR, 1, __ATOMIC_RELAXED, __HIP_MEMORY_SCOPE_AGENT);
  }

  for (int t = 1; t < T_SEQ; ++t) {
    if (wave == 0) {
      const int* f0 = flags + lane * FSTR;
      const int* f1 = flags + (lane + 64) * FSTR;
      bool ok;
      do {
        int a = __hip_atomic_load(f0, __ATOMIC_RELAXED, __HIP_MEMORY_SCOPE_AGENT);
        int c = __hip_atomic_load(f1, __ATOMIC_RELAXED, __HIP_MEMORY_SCOPE_AGENT);
        ok = (a >= t) && (c >= t);
      } while (!__all(ok));
    }
    __syncthreads();

    float u = 0.f;
    if (tid < ROWS) u = out[(size_t)t * N_RES + row0 + tid];

    const float* xrow = out + (size_t)(t - 1) * N_RES + tid;
    float x[8];
    #pragma unroll
    for (int j = 0; j < 8; ++j)
      x[j] = __hip_atomic_load(xrow + j * 256, __ATOMIC_RELAXED, __HIP_MEMORY_SCOPE_AGENT);

    float acc[ROWS];
    #pragma unroll
    for (int r = 0; r < ROWS; ++r) {
      acc[r] = w[r][0]*x[0] + w[r][1]*x[1] + w[r][2]*x[2] + w[r][3]*x[3]
             + w[r][4]*x[4] + w[r][5]*x[5] + w[r][6]*x[6] + w[r][7]*x[7];
    }
    #pragma unroll
    for (int m = 1; m < 64; m <<= 1) {
      #pragma unroll
      for (int r = 0; r < ROWS; ++r)
        acc[r] += __shfl_xor(acc[r], m, 64);
    }
    if (lane == 0) {
      #pragma unroll
      for (int r = 0; r < ROWS; ++r) red[r][wave] = acc[r];
    }
    __syncthreads();
    if (tid < ROWS) {
      float s = red[tid][0] + red[tid][1] + red[tid][2] + red[tid][3];
      __hip_atomic_store(out + (size_t)t * N_RES + row0 + tid, erff(u + s) * inv,
                         __ATOMIC_RELAXED, __HIP_MEMORY_SCOPE_AGENT);
    }
    if (wave == 0) {
      asm volatile("s_waitcnt vmcnt(0)" ::: "memory");
      if (lane == 0)
        __hip_atomic_store(flags + b * FSTR, t + 1,
                           __ATOMIC_RELAXED, __HIP_MEMORY_SCOPE_AGENT);
    }
  }
}

extern "C" void kernel_launch(void* const* d_in, const int* in_sizes, int n_in,
                              void* d_out, int out_size, void* d_ws, size_t ws_size,
                              hipStream_t stream)
{
  const float* input = (const float*)d_in[0];
  const float* w_in  = (const float*)d_in[1];
  const float* w_res = (const float*)d_in[2];
  float* out = (float*)d_out;

  const size_t xbytes = (size_t)T_SEQ * N_RES * sizeof(float);  // 16 MiB

  if (ws_size >= 8 * xbytes) {
    unsigned int* xbuf = (unsigned int*)d_ws;
    (void)hipMemsetAsync(d_ws, 0x7F, 8 * xbytes, stream);   // sentinel
    void* args[] = { (void*)&input, (void*)&w_in, (void*)&w_res,
                     (void*)&out, (void*)&xbuf };
    (void)hipLaunchCooperativeKernel((void*)esn_recur_v13<8>, dim3(NB), dim3(256),
                                     args, 0, stream);
  } else if (ws_size >= 4 * xbytes) {
    unsigned int* xbuf = (unsigned int*)d_ws;
    (void)hipMemsetAsync(d_ws, 0x7F, 4 * xbytes, stream);   // sentinel
    void* args[] = { (void*)&input, (void*)&w_in, (void*)&w_res,
                     (void*)&out, (void*)&xbuf };
    (void)hipLaunchCooperativeKernel((void*)esn_recur_v13<4>, dim3(NB), dim3(256),
                                     args, 0, stream);
  } else {
    dim3 g1(N_RES / 64, T_SEQ / 64), b1(256);
    hipLaunchKernelGGL(u_gemm, g1, b1, 0, stream, input, w_in, out);
    int* ws = (int*)d_ws;
    size_t clr = ws_size < 4096 ? ws_size : 4096;
    (void)hipMemsetAsync(d_ws, 0, clr, stream);
    void* args[] = { (void*)&w_res, (void*)&out, (void*)&ws };
    (void)hipLaunchCooperativeKernel((void*)esn_recur_flags, dim3(NB), dim3(256),
                                     args, 0, stream);
  }
}

// Round 2
// 4015.347 us; speedup vs baseline: 1.8679x; 1.8679x over previous
//
#include <hip/hip_runtime.h>
#include <math.h>

#define N_RES 2048
#define N_IN  128
#define T_SEQ 2048
#define NB    128      // blocks in recurrence kernel
#define ROWS  16       // rows per block
#define RREP  4        // x replicas (reader fan-in 128 -> 32 per line)
#define SLOTS 2        // double-buffered tagged x arena

// ---------------- Kernel 1: U = input @ W_in^T  -> d_out (row t = U[t]) ----
__global__ __launch_bounds__(256) void u_gemm(
    const float* __restrict__ in, const float* __restrict__ win,
    float* __restrict__ out)
{
  __shared__ float As[64][65];
  __shared__ float Bs[64][65];
  const int tid = threadIdx.x;
  const int t0 = blockIdx.y * 64;
  const int n0 = blockIdx.x * 64;
  const int tx = tid & 15, ty = tid >> 4;

  float acc[4][4];
  #pragma unroll
  for (int r = 0; r < 4; ++r)
    #pragma unroll
    for (int c = 0; c < 4; ++c) acc[r][c] = 0.f;

  for (int k0 = 0; k0 < N_IN; k0 += 64) {
    __syncthreads();
    #pragma unroll
    for (int i = 0; i < 4; ++i) {
      int idx = tid + i * 256;
      int row = idx >> 4;
      int k4  = (idx & 15) << 2;
      float4 a = *(const float4*)(in  + (size_t)(t0 + row) * N_IN + k0 + k4);
      As[row][k4+0] = a.x; As[row][k4+1] = a.y; As[row][k4+2] = a.z; As[row][k4+3] = a.w;
      float4 b = *(const float4*)(win + (size_t)(n0 + row) * N_IN + k0 + k4);
      Bs[row][k4+0] = b.x; Bs[row][k4+1] = b.y; Bs[row][k4+2] = b.z; Bs[row][k4+3] = b.w;
    }
    __syncthreads();
    for (int k = 0; k < 64; ++k) {
      float a[4], b[4];
      #pragma unroll
      for (int r = 0; r < 4; ++r) a[r] = As[ty*4+r][k];
      #pragma unroll
      for (int c = 0; c < 4; ++c) b[c] = Bs[tx*4+c][k];
      #pragma unroll
      for (int r = 0; r < 4; ++r)
        #pragma unroll
        for (int c = 0; c < 4; ++c) acc[r][c] += a[r] * b[c];
    }
  }
  #pragma unroll
  for (int r = 0; r < 4; ++r) {
    float4 v = make_float4(acc[r][0], acc[r][1], acc[r][2], acc[r][3]);
    *(float4*)(out + (size_t)(t0 + ty*4 + r) * N_RES + n0 + tx*4) = v;
  }
}

// ---- DPP helpers ----------------------------------------------------------
template<int CTRL>
__device__ __forceinline__ float xdpp(float v)
{
  return __uint_as_float(__builtin_amdgcn_update_dpp(
      0, (int)__float_as_uint(v), CTRL, 0xF, 0xF, true));
}
// quad_perm[1,0,3,2] (xor1) = 0xB1 ; quad_perm[2,3,0,1] (xor2) = 0x4E
// row_ror:8 = 0x128 : within 16-lane rows, (i+8)%16 == i^8

// ---- fold-and-keep wave reduction: 16 partials -> 1 full row sum per lane.
// Lane L ends with the complete sum of row rml(L) =
// (L&1)*8 + ((L>>1)&1)*4 + ((L>>2)&1)*2 + ((L>>3)&1)  (bijection on 0..15
// for lanes 0..15, duplicated x4 across the wave).
__device__ __forceinline__ float fold_reduce16(float v[16], int lane)
{
  #pragma unroll
  for (int r = 0; r < 8; ++r) {
    float send = (lane & 1) ? v[r] : v[r + 8];
    float recv = xdpp<0xB1>(send);
    v[r] = ((lane & 1) ? v[r + 8] : v[r]) + recv;
  }
  #pragma unroll
  for (int r = 0; r < 4; ++r) {
    float send = (lane & 2) ? v[r] : v[r + 4];
    float recv = xdpp<0x4E>(send);
    v[r] = ((lane & 2) ? v[r + 4] : v[r]) + recv;
  }
  #pragma unroll
  for (int r = 0; r < 2; ++r) {
    float send = (lane & 4) ? v[r] : v[r + 2];
    float recv = __shfl_xor(send, 4, 64);
    v[r] = ((lane & 4) ? v[r + 2] : v[r]) + recv;
  }
  {
    float send = (lane & 8) ? v[0] : v[1];
    float recv = xdpp<0x128>(send);          // xor8 within 16-lane row
    v[0] = ((lane & 8) ? v[1] : v[0]) + recv;
  }
  v[0] += __shfl_xor(v[0], 16, 64);
  v[0] += __shfl_xor(v[0], 32, 64);
  return v[0];
}

// ---- branchless fast erf (A&S 7.1.26), abs err <= 1.5e-7 ------------------
// 1/x via v_rcp_f32 (1 ULP, well below poly error): removes the
// div_scale/div_fmas/div_fixup sequence from the finalize critical path.
// exp underflow at large |a| gives exactly +-1.
__device__ __forceinline__ float fast_erf(float a)
{
  float ax = fabsf(a);
  float t  = __builtin_amdgcn_rcpf(fmaf(0.3275911f, ax, 1.0f));
  float p  = fmaf(1.061405429f, t, -1.453152027f);
  p = fmaf(p, t, 1.421413741f);
  p = fmaf(p, t, -0.284496736f);
  p = fmaf(p, t, 0.254829592f);
  p *= t;
  float e = __expf(-ax * ax);
  float r = fmaf(-p, e, 1.0f);
  return copysignf(r, a);
}

// ---------------- Kernel 2: recurrence v14 (= v12 + tagged LLC arena) ------
// 128 blocks x 256 threads. Block b owns rows [16b,16b+16); thread t owns
// cols {t+256j}. Validity = step tag, not sentinel bits: each x word is a
// u64 {hi=step tag, lo=f32 bits} stored atomically. Arena is double-buffered
// (slot = t&1), RREP replicas: 2*4*2048*8B = 128 KiB total -> permanently
// LLC-resident, so poll rounds run at LLC latency, not HBM (v12's 64 MiB
// fresh-line sentinel arena missed LLC: FETCH showed ~145 MB of poll-miss
// HBM traffic). Distance-2 slot reuse is race-free: publishing step t+1
// requires having consumed all of step t, which requires every block to have
// exited its step t-1 poll.
__global__ __launch_bounds__(256, 1) void esn_recur_v14(
    const float* __restrict__ wres, float* __restrict__ out,
    unsigned long long* __restrict__ xtag)
{
  const int tid = threadIdx.x;
  const int lane = tid & 63;
  const int row0 = blockIdx.x * ROWS;
  const int wave = tid >> 6;
  const float inv = 0.022097086912079608f;   // 1/sqrt(2048)
  const int rml = (lane & 1) * 8 + ((lane >> 1) & 1) * 4
                + ((lane >> 2) & 1) * 2 + ((lane >> 3) & 1);
  const int rb = blockIdx.x & (RREP - 1);    // replica this block polls

  // W: w[r][j] = W[row0+r][tid + 256*j]; coalesced, register-resident.
  float w[ROWS][8];
  #pragma unroll
  for (int r = 0; r < ROWS; ++r) {
    const float* p = wres + (size_t)(row0 + r) * N_RES + tid;
    #pragma unroll
    for (int j = 0; j < 8; ++j) w[r][j] = p[j * 256];
  }

  __shared__ float red[2][4][ROWS];   // [t&1][wave][row] — conflict-free

  // t = 0: x0 = erf(U[0]) * inv; publish tagged word to all replicas, slot 0
  if (tid < ROWS) {
    float x0 = fast_erf(out[row0 + tid]) * inv;
    unsigned long long wv = (unsigned long long)__float_as_uint(x0); // tag 0
    for (int rep = 0; rep < RREP; ++rep)
      __hip_atomic_store(xtag + (size_t)rep * N_RES + row0 + tid, wv,
                         __ATOMIC_RELAXED, __HIP_MEMORY_SCOPE_AGENT);
    out[row0 + tid] = x0;
  }
  __syncthreads();

  for (int t = 1; t < T_SEQ; ++t) {
    const int p = t & 1;
    // own U[t] slot for row rml — issued before the poll, hides under it
    float u = out[(size_t)t * N_RES + row0 + rml];

    // ---- poll own 8 x words of row t-1 (tag test), prio 0 ----------------
    const unsigned long long* xr = xtag
        + ((size_t)((t - 1) & 1) * RREP + rb) * N_RES + tid;
    const unsigned int want = (unsigned int)(t - 1);
    unsigned long long xb[8];
    unsigned int orv;
    do {
      #pragma unroll
      for (int j = 0; j < 8; ++j)
        xb[j] = __hip_atomic_load(xr + (size_t)j * 256, __ATOMIC_RELAXED,
                                  __HIP_MEMORY_SCOPE_AGENT);
      orv  = ((unsigned int)(xb[0] >> 32) ^ want)
           | ((unsigned int)(xb[1] >> 32) ^ want)
           | ((unsigned int)(xb[2] >> 32) ^ want)
           | ((unsigned int)(xb[3] >> 32) ^ want);
      orv |= ((unsigned int)(xb[4] >> 32) ^ want)
           | ((unsigned int)(xb[5] >> 32) ^ want)
           | ((unsigned int)(xb[6] >> 32) ^ want)
           | ((unsigned int)(xb[7] >> 32) ^ want);
    } while (orv != 0u);

    asm volatile("s_setprio 3" ::: "memory");   // critical path begins

    // partial matvec: 16 rows x 8 cols (x = low dword of each tagged word)
    float x0 = __uint_as_float((unsigned int)xb[0]);
    float x1 = __uint_as_float((unsigned int)xb[1]);
    float x2 = __uint_as_float((unsigned int)xb[2]);
    float x3 = __uint_as_float((unsigned int)xb[3]);
    float x4 = __uint_as_float((unsigned int)xb[4]);
    float x5 = __uint_as_float((unsigned int)xb[5]);
    float x6 = __uint_as_float((unsigned int)xb[6]);
    float x7 = __uint_as_float((unsigned int)xb[7]);
    float acc[ROWS];
    #pragma unroll
    for (int r = 0; r < ROWS; ++r) {
      acc[r] = w[r][0]*x0 + w[r][1]*x1 + w[r][2]*x2 + w[r][3]*x3
             + w[r][4]*x4 + w[r][5]*x5 + w[r][6]*x6 + w[r][7]*x7;
    }
    float s = fold_reduce16(acc, lane);   // lane holds full sum of row rml

    if (wave != 0 && lane < ROWS) red[p][wave][rml] = s;
    __syncthreads();

    // wave 0, lanes 0..15 finalize row rml (bijection; consistent with u)
    if (tid < ROWS) {
      float tot = s + red[p][1][rml] + red[p][2][rml] + red[p][3][rml];
      float xt = fast_erf(u + tot) * inv;
      unsigned long long wv = ((unsigned long long)(unsigned int)t << 32)
                            | (unsigned long long)__float_as_uint(xt);
      unsigned long long* dst = xtag + (size_t)(t & 1) * RREP * N_RES
                              + row0 + rml;
      #pragma unroll
      for (int rep = 0; rep < RREP; ++rep)
        __hip_atomic_store(dst + (size_t)rep * N_RES, wv,
                           __ATOMIC_RELAXED, __HIP_MEMORY_SCOPE_AGENT);
      out[(size_t)t * N_RES + row0 + rml] = xt;   // plain; after signals
    }
    asm volatile("s_setprio 0" ::: "memory");   // back to poll priority
    // parity LDS buffer + barrier ordering bounds skew <= 1 step
  }
}

// ---------------- fallback (R2 flag barrier) if ws too small ---------------
#define FSTR 4
__global__ __launch_bounds__(256, 1) void esn_recur_flags(
    const float* __restrict__ wres, float* out, int* ws)
{
  const int b = blockIdx.x;
  const int tid = threadIdx.x;
  const int lane = tid & 63;
  const int wave = tid >> 6;
  const int row0 = b * ROWS;
  const float inv = 0.022097086912079608f;

  float w[ROWS][8];
  #pragma unroll
  for (int r = 0; r < ROWS; ++r) {
    const float* p = wres + (size_t)(row0 + r) * N_RES + tid;
    #pragma unroll
    for (int j = 0; j < 8; ++j) w[r][j] = p[j * 256];
  }

  __shared__ float red[ROWS][4];
  int* flags = ws;

  if (tid < ROWS) {
    float u = out[row0 + tid];
    __hip_atomic_store(out + row0 + tid, erff(u) * inv,
                       __ATOMIC_RELAXED, __HIP_MEMORY_SCOPE_AGENT);
  }
  if (wave == 0) {
    asm volatile("s_waitcnt vmcnt(0)" ::: "memory");
    if (lane == 0)
      __hip_atomic_store(flags + b * FSTR, 1, __ATOMIC_RELAXED, __HIP_MEMORY_SCOPE_AGENT);
  }

  for (int t = 1; t < T_SEQ; ++t) {
    if (wave == 0) {
      const int* f0 = flags + lane * FSTR;
      const int* f1 = flags + (lane + 64) * FSTR;
      bool ok;
      do {
        int a = __hip_atomic_load(f0, __ATOMIC_RELAXED, __HIP_MEMORY_SCOPE_AGENT);
        int c = __hip_atomic_load(f1, __ATOMIC_RELAXED, __HIP_MEMORY_SCOPE_AGENT);
        ok = (a >= t) && (c >= t);
      } while (!__all(ok));
    }
    __syncthreads();

    float u = 0.f;
    if (tid < ROWS) u = out[(size_t)t * N_RES + row0 + tid];

    const float* xrow = out + (size_t)(t - 1) * N_RES + tid;
    float x[8];
    #pragma unroll
    for (int j = 0; j < 8; ++j)
      x[j] = __hip_atomic_load(xrow + j * 256, __ATOMIC_RELAXED, __HIP_MEMORY_SCOPE_AGENT);

    float acc[ROWS];
    #pragma unroll
    for (int r = 0; r < ROWS; ++r) {
      acc[r] = w[r][0]*x[0] + w[r][1]*x[1] + w[r][2]*x[2] + w[r][3]*x[3]
             + w[r][4]*x[4] + w[r][5]*x[5] + w[r][6]*x[6] + w[r][7]*x[7];
    }
    #pragma unroll
    for (int m = 1; m < 64; m <<= 1) {
      #pragma unroll
      for (int r = 0; r < ROWS; ++r)
        acc[r] += __shfl_xor(acc[r], m, 64);
    }
    if (lane == 0) {
      #pragma unroll
      for (int r = 0; r < ROWS; ++r) red[r][wave] = acc[r];
    }
    __syncthreads();
    if (tid < ROWS) {
      float s = red[tid][0] + red[tid][1] + red[tid][2] + red[tid][3];
      __hip_atomic_store(out + (size_t)t * N_RES + row0 + tid, erff(u + s) * inv,
                         __ATOMIC_RELAXED, __HIP_MEMORY_SCOPE_AGENT);
    }
    if (wave == 0) {
      asm volatile("s_waitcnt vmcnt(0)" ::: "memory");
      if (lane == 0)
        __hip_atomic_store(flags + b * FSTR, t + 1,
                           __ATOMIC_RELAXED, __HIP_MEMORY_SCOPE_AGENT);
    }
  }
}

extern "C" void kernel_launch(void* const* d_in, const int* in_sizes, int n_in,
                              void* d_out, int out_size, void* d_ws, size_t ws_size,
                              hipStream_t stream)
{
  const float* input = (const float*)d_in[0];
  const float* w_in  = (const float*)d_in[1];
  const float* w_res = (const float*)d_in[2];
  float* out = (float*)d_out;

  const size_t arena = (size_t)SLOTS * RREP * N_RES * sizeof(unsigned long long);
  // 128 KiB tagged x arena

  dim3 g1(N_RES / 64, T_SEQ / 64), b1(256);
  hipLaunchKernelGGL(u_gemm, g1, b1, 0, stream, input, w_in, out);

  if (ws_size >= arena) {
    unsigned long long* xtag = (unsigned long long*)d_ws;
    (void)hipMemsetAsync(d_ws, 0xFF, arena, stream);  // tag 0xFFFFFFFF != any t
    void* args[] = { (void*)&w_res, (void*)&out, (void*)&xtag };
    (void)hipLaunchCooperativeKernel((void*)esn_recur_v14, dim3(NB), dim3(256),
                                     args, 0, stream);
  } else {
    int* ws = (int*)d_ws;
    size_t clr = ws_size < 4096 ? ws_size : 4096;
    (void)hipMemsetAsync(d_ws, 0, clr, stream);
    void* args[] = { (void*)&w_res, (void*)&out, (void*)&ws };
    (void)hipLaunchCooperativeKernel((void*)esn_recur_flags, dim3(NB), dim3(256),
                                     args, 0, stream);
  }
}

// Round 3
// 3032.046 us; speedup vs baseline: 2.4736x; 1.3243x over previous
//
#include <hip/hip_runtime.h>
#include <math.h>

#define N_RES 2048
#define N_IN  128
#define T_SEQ 2048
#define NB    128      // blocks in recurrence kernel
#define ROWS  16       // rows per block
#define RREP  4        // x replicas (reader fan-in 128 -> 32 per line)
#define SENT  0x7F7F7F7Fu   // sentinel (3.39e38); bit30 set. |x|<=0.0222 -> bit30 clear

// ---------------- Kernel 1: U = input @ W_in^T (fallback path only) -------
__global__ __launch_bounds__(256) void u_gemm(
    const float* __restrict__ in, const float* __restrict__ win,
    float* __restrict__ out)
{
  __shared__ float As[64][65];
  __shared__ float Bs[64][65];
  const int tid = threadIdx.x;
  const int t0 = blockIdx.y * 64;
  const int n0 = blockIdx.x * 64;
  const int tx = tid & 15, ty = tid >> 4;

  float acc[4][4];
  #pragma unroll
  for (int r = 0; r < 4; ++r)
    #pragma unroll
    for (int c = 0; c < 4; ++c) acc[r][c] = 0.f;

  for (int k0 = 0; k0 < N_IN; k0 += 64) {
    __syncthreads();
    #pragma unroll
    for (int i = 0; i < 4; ++i) {
      int idx = tid + i * 256;
      int row = idx >> 4;
      int k4  = (idx & 15) << 2;
      float4 a = *(const float4*)(in  + (size_t)(t0 + row) * N_IN + k0 + k4);
      As[row][k4+0] = a.x; As[row][k4+1] = a.y; As[row][k4+2] = a.z; As[row][k4+3] = a.w;
      float4 b = *(const float4*)(win + (size_t)(n0 + row) * N_IN + k0 + k4);
      Bs[row][k4+0] = b.x; Bs[row][k4+1] = b.y; Bs[row][k4+2] = b.z; Bs[row][k4+3] = b.w;
    }
    __syncthreads();
    for (int k = 0; k < 64; ++k) {
      float a[4], b[4];
      #pragma unroll
      for (int r = 0; r < 4; ++r) a[r] = As[ty*4+r][k];
      #pragma unroll
      for (int c = 0; c < 4; ++c) b[c] = Bs[tx*4+c][k];
      #pragma unroll
      for (int r = 0; r < 4; ++r)
        #pragma unroll
        for (int c = 0; c < 4; ++c) acc[r][c] += a[r] * b[c];
    }
  }
  #pragma unroll
  for (int r = 0; r < 4; ++r) {
    float4 v = make_float4(acc[r][0], acc[r][1], acc[r][2], acc[r][3]);
    *(float4*)(out + (size_t)(t0 + ty*4 + r) * N_RES + n0 + tx*4) = v;
  }
}

// ---- DPP helpers ----------------------------------------------------------
template<int CTRL>
__device__ __forceinline__ float xdpp(float v)
{
  return __uint_as_float(__builtin_amdgcn_update_dpp(
      0, (int)__float_as_uint(v), CTRL, 0xF, 0xF, true));
}
// quad_perm[1,0,3,2] (xor1) = 0xB1 ; quad_perm[2,3,0,1] (xor2) = 0x4E
// row_ror:8 = 0x128 : within 16-lane rows, (i+8)%16 == i^8

// ---- fold-and-keep wave reduction: 16 partials -> 1 full row sum per lane.
// Lane L ends with the complete sum of row rml(L) =
// (L&1)*8 + ((L>>1)&1)*4 + ((L>>2)&1)*2 + ((L>>3)&1)  (bijection on 0..15
// for lanes 0..15, duplicated x4 across the wave).
__device__ __forceinline__ float fold_reduce16(float v[16], int lane)
{
  #pragma unroll
  for (int r = 0; r < 8; ++r) {
    float send = (lane & 1) ? v[r] : v[r + 8];
    float recv = xdpp<0xB1>(send);
    v[r] = ((lane & 1) ? v[r + 8] : v[r]) + recv;
  }
  #pragma unroll
  for (int r = 0; r < 4; ++r) {
    float send = (lane & 2) ? v[r] : v[r + 4];
    float recv = xdpp<0x4E>(send);
    v[r] = ((lane & 2) ? v[r + 4] : v[r]) + recv;
  }
  #pragma unroll
  for (int r = 0; r < 2; ++r) {
    float send = (lane & 4) ? v[r] : v[r + 2];
    float recv = __shfl_xor(send, 4, 64);
    v[r] = ((lane & 4) ? v[r + 2] : v[r]) + recv;
  }
  {
    float send = (lane & 8) ? v[0] : v[1];
    float recv = xdpp<0x128>(send);          // xor8 within 16-lane row
    v[0] = ((lane & 8) ? v[1] : v[0]) + recv;
  }
  v[0] += __shfl_xor(v[0], 16, 64);
  v[0] += __shfl_xor(v[0], 32, 64);
  return v[0];
}

// ---- branchless fast erf (A&S 7.1.26), abs err <= 1.5e-7 ------------------
// 1/x via v_rcp_f32 (1 ULP, well below poly error): removes the
// div_scale/div_fmas/div_fixup sequence from the finalize critical path.
// Validated R1/R2: absmax identical to precise-div version (1.22e-4).
__device__ __forceinline__ float fast_erf(float a)
{
  float ax = fabsf(a);
  float t  = __builtin_amdgcn_rcpf(fmaf(0.3275911f, ax, 1.0f));
  float p  = fmaf(1.061405429f, t, -1.453152027f);
  p = fmaf(p, t, 1.421413741f);
  p = fmaf(p, t, -0.284496736f);
  p = fmaf(p, t, 0.254829592f);
  p *= t;
  float e = __expf(-ax * ax);
  float r = fmaf(-p, e, 1.0f);
  return copysignf(r, a);
}

// ---------------- Kernel 2: recurrence v15 (= v12 substrate + fused U) -----
// 128 blocks x 256 threads. Block b owns rows [16b,16b+16); thread t owns
// cols {t+256j}. Data-as-flag 4B sentinel, fresh lines per step, RREP=4,
// one barrier/step, parity LDS combine, setprio 3 on the post-detect path —
// byte-identical signaling to v12 (best measured: 3035 us). New vs v12:
//   (a) U computed in-kernel in the post-publish dead window (removes the
//       u_gemm dispatch): each thread holds a 32-float W_in slice for row
//       row0+rml, chunk lane>>4; u(t+1) = 8x float4 L2-hot loads + 32 FMAs
//       + xor16/xor32 shuffles. Nothing added between detect and publish.
//   (b) rcp-based fast_erf on the finalize path.
__global__ __launch_bounds__(256, 1) void esn_recur_v15(
    const float* __restrict__ in, const float* __restrict__ win,
    const float* __restrict__ wres, float* __restrict__ out,
    unsigned int* __restrict__ xbuf)
{
  const int tid = threadIdx.x;
  const int lane = tid & 63;
  const int row0 = blockIdx.x * ROWS;
  const int wave = tid >> 6;
  const float inv = 0.022097086912079608f;   // 1/sqrt(2048)
  const int rml = (lane & 1) * 8 + ((lane >> 1) & 1) * 4
                + ((lane >> 2) & 1) * 2 + ((lane >> 3) & 1);
  const int rb = blockIdx.x & (RREP - 1);    // replica this block polls

  // ---- W_in slice: wiA[k] = W_in[row0+rml][(lane>>4)*32 + k] -------------
  float wiA[32];
  {
    const float* wp = win + (size_t)(row0 + rml) * N_IN + ((lane >> 4) << 5);
    #pragma unroll
    for (int q = 0; q < 8; ++q) {
      float4 v = *(const float4*)(wp + 4 * q);
      wiA[4*q+0] = v.x; wiA[4*q+1] = v.y; wiA[4*q+2] = v.z; wiA[4*q+3] = v.w;
    }
  }

  // ---- u0 + x0 publish FIRST (unblocks everyone's t=1 poll early) --------
  {
    const float* ip = in + ((lane >> 4) << 5);
    float uv = 0.f;
    #pragma unroll
    for (int q = 0; q < 8; ++q) {
      float4 iv = *(const float4*)(ip + 4 * q);
      uv = fmaf(wiA[4*q+0], iv.x, uv); uv = fmaf(wiA[4*q+1], iv.y, uv);
      uv = fmaf(wiA[4*q+2], iv.z, uv); uv = fmaf(wiA[4*q+3], iv.w, uv);
    }
    uv += __shfl_xor(uv, 16, 64);
    uv += __shfl_xor(uv, 32, 64);
    if (tid < ROWS) {
      float x0 = fast_erf(uv) * inv;
      unsigned int xu = __float_as_uint(x0);
      #pragma unroll
      for (int rep = 0; rep < RREP; ++rep)
        __hip_atomic_store(xbuf + (size_t)rep * N_RES + row0 + rml, xu,
                           __ATOMIC_RELAXED, __HIP_MEMORY_SCOPE_AGENT);
      out[row0 + rml] = x0;
    }
  }

  // ---- W_res: w[r][j] = W[row0+r][tid + 256*j]; register/AGPR-resident ---
  float w[ROWS][8];
  #pragma unroll
  for (int r = 0; r < ROWS; ++r) {
    const float* p = wres + (size_t)(row0 + r) * N_RES + tid;
    #pragma unroll
    for (int j = 0; j < 8; ++j) w[r][j] = p[j * 256];
  }

  __shared__ float red[2][4][ROWS];   // [t&1][wave][row] — conflict-free

  // u for t=1
  float u;
  {
    const float* ip = in + N_IN + ((lane >> 4) << 5);
    float uv = 0.f;
    #pragma unroll
    for (int q = 0; q < 8; ++q) {
      float4 iv = *(const float4*)(ip + 4 * q);
      uv = fmaf(wiA[4*q+0], iv.x, uv); uv = fmaf(wiA[4*q+1], iv.y, uv);
      uv = fmaf(wiA[4*q+2], iv.z, uv); uv = fmaf(wiA[4*q+3], iv.w, uv);
    }
    uv += __shfl_xor(uv, 16, 64);
    uv += __shfl_xor(uv, 32, 64);
    u = uv;
  }
  __syncthreads();

  for (int t = 1; t < T_SEQ; ++t) {
    const int p = t & 1;

    // ---- poll own 8 x words of row t-1 (bit-30 sentinel test), prio 0 ----
    const unsigned int* xr = xbuf + ((size_t)(t - 1) * RREP + rb) * N_RES + tid;
    unsigned int xb[8];
    unsigned int orv;
    do {
      #pragma unroll
      for (int j = 0; j < 8; ++j)
        xb[j] = __hip_atomic_load(xr + j * 256, __ATOMIC_RELAXED,
                                  __HIP_MEMORY_SCOPE_AGENT);
      orv  = (xb[0] | xb[1]) | (xb[2] | xb[3]);
      orv |= (xb[4] | xb[5]) | (xb[6] | xb[7]);
    } while (orv & 0x40000000u);

    asm volatile("s_setprio 3" ::: "memory");   // critical path begins

    // partial matvec: 16 rows x 8 cols
    float acc[ROWS];
    #pragma unroll
    for (int r = 0; r < ROWS; ++r) {
      acc[r] = w[r][0]*__uint_as_float(xb[0]) + w[r][1]*__uint_as_float(xb[1])
             + w[r][2]*__uint_as_float(xb[2]) + w[r][3]*__uint_as_float(xb[3])
             + w[r][4]*__uint_as_float(xb[4]) + w[r][5]*__uint_as_float(xb[5])
             + w[r][6]*__uint_as_float(xb[6]) + w[r][7]*__uint_as_float(xb[7]);
    }
    float s = fold_reduce16(acc, lane);   // lane holds full sum of row rml

    if (wave != 0 && lane < ROWS) red[p][wave][rml] = s;
    __syncthreads();

    // wave 0, lanes 0..15 finalize row rml (u held in register, same lane)
    if (tid < ROWS) {
      float tot = s + red[p][1][rml] + red[p][2][rml] + red[p][3][rml];
      float xt = fast_erf(u + tot) * inv;
      unsigned int xu = __float_as_uint(xt);
      unsigned int* dst = xbuf + (size_t)t * RREP * N_RES + row0 + rml;
      #pragma unroll
      for (int rep = 0; rep < RREP; ++rep)
        __hip_atomic_store(dst + (size_t)rep * N_RES, xu,
                           __ATOMIC_RELAXED, __HIP_MEMORY_SCOPE_AGENT);
      out[(size_t)t * N_RES + row0 + rml] = xt;   // plain; after signals
    }
    asm volatile("s_setprio 0" ::: "memory");   // back to poll priority

    // ---- u for t+1: dead-window work (all other blocks still finishing) --
    {
      int tn = (t + 1) & (T_SEQ - 1);           // t+1, wraps harmlessly at end
      const float* ip = in + (size_t)tn * N_IN + ((lane >> 4) << 5);
      float uv = 0.f;
      #pragma unroll
      for (int q = 0; q < 8; ++q) {
        float4 iv = *(const float4*)(ip + 4 * q);
        uv = fmaf(wiA[4*q+0], iv.x, uv); uv = fmaf(wiA[4*q+1], iv.y, uv);
        uv = fmaf(wiA[4*q+2], iv.z, uv); uv = fmaf(wiA[4*q+3], iv.w, uv);
      }
      uv += __shfl_xor(uv, 16, 64);
      uv += __shfl_xor(uv, 32, 64);
      u = uv;
    }
    // parity LDS buffer + barrier ordering bounds skew <= 1 step
  }
}

// ---------------- fallback (R2 flag barrier) if ws too small ---------------
#define FSTR 4
__global__ __launch_bounds__(256, 1) void esn_recur_flags(
    const float* __restrict__ wres, float* out, int* ws)
{
  const int b = blockIdx.x;
  const int tid = threadIdx.x;
  const int lane = tid & 63;
  const int wave = tid >> 6;
  const int row0 = b * ROWS;
  const float inv = 0.022097086912079608f;

  float w[ROWS][8];
  #pragma unroll
  for (int r = 0; r < ROWS; ++r) {
    const float* p = wres + (size_t)(row0 + r) * N_RES + tid;
    #pragma unroll
    for (int j = 0; j < 8; ++j) w[r][j] = p[j * 256];
  }

  __shared__ float red[ROWS][4];
  int* flags = ws;

  if (tid < ROWS) {
    float u = out[row0 + tid];
    __hip_atomic_store(out + row0 + tid, erff(u) * inv,
                       __ATOMIC_RELAXED, __HIP_MEMORY_SCOPE_AGENT);
  }
  if (wave == 0) {
    asm volatile("s_waitcnt vmcnt(0)" ::: "memory");
    if (lane == 0)
      __hip_atomic_store(flags + b * FSTR, 1, __ATOMIC_RELAXED, __HIP_MEMORY_SCOPE_AGENT);
  }

  for (int t = 1; t < T_SEQ; ++t) {
    if (wave == 0) {
      const int* f0 = flags + lane * FSTR;
      const int* f1 = flags + (lane + 64) * FSTR;
      bool ok;
      do {
        int a = __hip_atomic_load(f0, __ATOMIC_RELAXED, __HIP_MEMORY_SCOPE_AGENT);
        int c = __hip_atomic_load(f1, __ATOMIC_RELAXED, __HIP_MEMORY_SCOPE_AGENT);
        ok = (a >= t) && (c >= t);
      } while (!__all(ok));
    }
    __syncthreads();

    float u = 0.f;
    if (tid < ROWS) u = out[(size_t)t * N_RES + row0 + tid];

    const float* xrow = out + (size_t)(t - 1) * N_RES + tid;
    float x[8];
    #pragma unroll
    for (int j = 0; j < 8; ++j)
      x[j] = __hip_atomic_load(xrow + j * 256, __ATOMIC_RELAXED, __HIP_MEMORY_SCOPE_AGENT);

    float acc[ROWS];
    #pragma unroll
    for (int r = 0; r < ROWS; ++r) {
      acc[r] = w[r][0]*x[0] + w[r][1]*x[1] + w[r][2]*x[2] + w[r][3]*x[3]
             + w[r][4]*x[4] + w[r][5]*x[5] + w[r][6]*x[6] + w[r][7]*x[7];
    }
    #pragma unroll
    for (int m = 1; m < 64; m <<= 1) {
      #pragma unroll
      for (int r = 0; r < ROWS; ++r)
        acc[r] += __shfl_xor(acc[r], m, 64);
    }
    if (lane == 0) {
      #pragma unroll
      for (int r = 0; r < ROWS; ++r) red[r][wave] = acc[r];
    }
    __syncthreads();
    if (tid < ROWS) {
      float s = red[tid][0] + red[tid][1] + red[tid][2] + red[tid][3];
      __hip_atomic_store(out + (size_t)t * N_RES + row0 + tid, erff(u + s) * inv,
                         __ATOMIC_RELAXED, __HIP_MEMORY_SCOPE_AGENT);
    }
    if (wave == 0) {
      asm volatile("s_waitcnt vmcnt(0)" ::: "memory");
      if (lane == 0)
        __hip_atomic_store(flags + b * FSTR, t + 1,
                           __ATOMIC_RELAXED, __HIP_MEMORY_SCOPE_AGENT);
    }
  }
}

extern "C" void kernel_launch(void* const* d_in, const int* in_sizes, int n_in,
                              void* d_out, int out_size, void* d_ws, size_t ws_size,
                              hipStream_t stream)
{
  const float* input = (const float*)d_in[0];
  const float* w_in  = (const float*)d_in[1];
  const float* w_res = (const float*)d_in[2];
  float* out = (float*)d_out;

  const size_t xbytes = (size_t)T_SEQ * N_RES * sizeof(float);  // 16 MiB

  if (ws_size >= (size_t)RREP * xbytes) {
    unsigned int* xbuf = (unsigned int*)d_ws;
    (void)hipMemsetAsync(d_ws, 0x7F, (size_t)RREP * xbytes, stream);  // sentinel
    void* args[] = { (void*)&input, (void*)&w_in, (void*)&w_res,
                     (void*)&out, (void*)&xbuf };
    (void)hipLaunchCooperativeKernel((void*)esn_recur_v15, dim3(NB), dim3(256),
                                     args, 0, stream);
  } else {
    dim3 g1(N_RES / 64, T_SEQ / 64), b1(256);
    hipLaunchKernelGGL(u_gemm, g1, b1, 0, stream, input, w_in, out);
    int* ws = (int*)d_ws;
    size_t clr = ws_size < 4096 ? ws_size : 4096;
    (void)hipMemsetAsync(d_ws, 0, clr, stream);
    void* args[] = { (void*)&w_res, (void*)&out, (void*)&ws };
    (void)hipLaunchCooperativeKernel((void*)esn_recur_flags, dim3(NB), dim3(256),
                                     args, 0, stream);
  }
}